// Round 6
// baseline (190.081 us; speedup 1.0000x reference)
//
#include <hip/hip_runtime.h>
#include <math.h>

#define LN_EPS 1e-5f
// 1/(3*sqrt(32))
#define KSCALE 0.058925565098878960f

__device__ __forceinline__ float ln_row(float x) {
    float m = x;
    #pragma unroll
    for (int off = 16; off > 0; off >>= 1) m += __shfl_xor(m, off, 32);
    m *= (1.0f / 32.0f);
    float c = x - m;
    float v = c * c;
    #pragma unroll
    for (int off = 16; off > 0; off >>= 1) v += __shfl_xor(v, off, 32);
    v *= (1.0f / 32.0f);
    return c * rsqrtf(v + LN_EPS);
}

__device__ __forceinline__ float rdlane(float v, int l) {
    return __int_as_float(__builtin_amdgcn_readlane(__float_as_int(v), l));
}

// Single dispatch, NO inter-block communication (R3/R4 showed device-memory
// sync costs 40-90us). 128 blocks x 1024 threads: b -> (h = b>>4, lq = b&15).
// Each block REDUNDANTLY computes its head's full Gram matrices (16x
// redundancy, zero sync), then finalizes rows l = lq*32..+31.
//
// Gram trick: mix[r] packs V (lanes 0-31) and Kn (lanes 32-63). Per d,
// kd = v_readlane(mix, 32+d) is an SGPR; one v_fmac acc_a[d] += kd*mix
// accumulates KV[d][e] in lower lanes AND KK[d][e] in upper lanes. Same for
// QQ via duplicated Q (upper half adds a 2nd copy -> GQQ holds 2x QQ,
// compensated by 0.25 factor in finalize).
//
// R5 bug (fixed): GKV is [d][m] layout (GKV[d][e]=sum_s K[s][d]V[s][e]);
// order1 must read the COLUMN GKV[e][m], not the row GKV[m][e]. KK/QQ are
// symmetric so only order1 was affected.
__global__ __launch_bounds__(1024) void fused_attn(
    const float* __restrict__ q_in, const float* __restrict__ k_in,
    const float* __restrict__ v_in, const float* __restrict__ key_len,
    float* __restrict__ out)
{
    __shared__ float mix[64][64];   // [r][0:32)=V[r][e], [r][32:64)=Kn[r][e]
    __shared__ float qdp[64][64];   // [r][e] and [r][32+e] both = Qn[r][e]
    __shared__ float GKV[32][33];   // GKV[d][e] = sum_s K[s][d]V[s][e], stride 33
    __shared__ float GKK[32][33];   // KK[d][e]
    __shared__ float GQQ[32][33];   // 2x QQ[d][e]
    __shared__ float GKsum[32];
    __shared__ float qsh[32][32];
    __shared__ float ksh[32][32];

    const int b = blockIdx.x;
    const int h = b >> 4;           // 0..7
    const int lq = b & 15;          // 0..15 -> rows lq*32..+31
    const int t = threadIdx.x;
    const int lane32 = t & 31;
    const int row32 = t >> 5;       // 0..31
    const int lane64 = t & 63;
    const int wv = t >> 6;          // wave 0..15

    // zero Gram LDS (chunk-loop __syncthreads below orders this before ds_adds)
    {
        float* g0 = &GKV[0][0];
        float* g1 = &GKK[0][0];
        float* g2 = &GQQ[0][0];
        for (int i = t; i < 32 * 33; i += 1024) { g0[i] = 0.f; g1[i] = 0.f; g2[i] = 0.f; }
        if (t < 32) GKsum[t] = 0.f;
    }

    float acc_a[32];   // lower lanes: KV[d][e]; upper lanes: KK[d][e]
    float acc_q[32];   // QQ[d][e] (both halves -> 2x after reduction)
    #pragma unroll
    for (int d = 0; d < 32; ++d) { acc_a[d] = 0.f; acc_q[d] = 0.f; }
    float acc_ks = 0.f;             // upper lanes: sum_s Kn[s][e]

    for (int c = 0; c < 8; ++c) {
        __syncthreads();            // previous chunk's Gram reads done
        #pragma unroll
        for (int p = 0; p < 2; ++p) {
            int r = row32 + p * 32;         // 0..63
            int s = c * 64 + r;
            int g = (s * 8 + h) * 32 + lane32;
            float kn = ln_row(k_in[g]) * (KSCALE * key_len[s]);
            float qn = ln_row(q_in[g]);
            float vv = v_in[g];
            mix[r][lane32] = vv;
            mix[r][32 + lane32] = kn;
            qdp[r][lane32] = qn;
            qdp[r][32 + lane32] = qn;
        }
        __syncthreads();
        // wave wv owns rows wv*4..+3 of this chunk (disjoint s across waves)
        #pragma unroll
        for (int i = 0; i < 4; ++i) {
            int r = wv * 4 + i;
            float vm_ = mix[r][lane64];
            float qm_ = qdp[r][lane64];
            acc_ks += vm_;          // upper half = Kn sum; lower half unused
            #pragma unroll
            for (int d = 0; d < 32; ++d) {
                float kd = rdlane(vm_, 32 + d);   // SGPR broadcast of Kn[r][d]
                float qd = rdlane(qm_, d);        // SGPR broadcast of Qn[r][d]
                acc_a[d] = fmaf(kd, vm_, acc_a[d]);
                acc_q[d] = fmaf(qd, qm_, acc_q[d]);
            }
        }
    }

    // reduce 16 waves' partials into LDS. Banks: (d*33+e)%32 = (d+e)%32,
    // distinct per lane within a half; lower/upper pairs 2-way (free).
    {
        int e = lane64 & 31;
        float* basea = (lane64 >= 32) ? &GKK[0][0] : &GKV[0][0];
        #pragma unroll
        for (int d = 0; d < 32; ++d) {
            atomicAdd(&basea[d * 33 + e], acc_a[d]);
            atomicAdd(&GQQ[d][e], acc_q[d]);      // both halves -> 2x QQ
        }
        if (lane64 >= 32) atomicAdd(&GKsum[e], acc_ks);
    }
    __syncthreads();

    // ---- finalize rows l = lq*32 + row32 ----
    const int l = lq * 32 + row32;
    const int gidx = (l * 8 + h) * 32 + lane32;
    float qd = ln_row(q_in[gidx]);
    float kd = ln_row(k_in[gidx]) * (KSCALE * key_len[l]);
    float vm = v_in[gidx];
    qsh[row32][lane32] = qd;
    ksh[row32][lane32] = kd;
    __syncthreads();

    float s1 = 0.f, s2 = 0.f, o1 = 0.f;
    #pragma unroll 8
    for (int e = 0; e < 32; ++e) {
        float qe = qsh[row32][e];
        s1 += GKK[lane32][e] * qe;            // (KK q)[d=lane]
        s2 += GQQ[lane32][e] * ksh[row32][e]; // (2*QQ k)[d=lane]
        o1 += GKV[e][lane32] * qe;            // order1[m=lane]: column read (fix)
    }
    float normp = qd * GKsum[lane32] + 0.5f * qd * s1;
    float kq2p = kd * s2;                      // = 2 * k^T QQ k after reduce
    #pragma unroll
    for (int off = 16; off > 0; off >>= 1) {
        normp += __shfl_xor(normp, off, 32);
        kq2p  += __shfl_xor(kq2p, off, 32);
    }
    out[gidx] = (o1 + 0.25f * kq2p * vm) / normp;   // 0.25 = 0.5 * (1/2x)
}

extern "C" void kernel_launch(void* const* d_in, const int* in_sizes, int n_in,
                              void* d_out, int out_size, void* d_ws, size_t ws_size,
                              hipStream_t stream) {
    const float* q_in    = (const float*)d_in[0];
    const float* k_in    = (const float*)d_in[1];
    const float* v_in    = (const float*)d_in[2];
    // d_in[3] attn_mask (unused), d_in[4] query_lengths (unused)
    const float* key_len = (const float*)d_in[5];
    float* out = (float*)d_out;
    // d_ws intentionally unused: no inter-block state of any kind.

    fused_attn<<<128, 1024, 0, stream>>>(q_in, k_in, v_in, key_len, out);
}